// Round 9
// baseline (276.334 us; speedup 1.0000x reference)
//
#include <hip/hip_runtime.h>
#include <hip/hip_bf16.h>

#define NEG_SLOPE 0.2f

typedef __attribute__((ext_vector_type(8))) short short8v;
typedef __attribute__((ext_vector_type(4))) float f32x4;

// ---------- bf16 round-to-nearest helpers ----------
__device__ __forceinline__ unsigned short f2bf(float f) {
    unsigned u = __float_as_uint(f);
    unsigned r = (u + 0x7FFFu + ((u >> 16) & 1u)) >> 16;
    return (unsigned short)r;
}
__device__ __forceinline__ float bf2f(unsigned short h) {
    return __uint_as_float((unsigned)h << 16);
}

// ---------- fused: histogram + weight split/transpose ----------
// blocks [0, histB): histogram of dst. blocks [histB, ...): split W1, W2.
__global__ __launch_bounds__(256) void hist_split_kernel(const int* __restrict__ dst,
                                                         int* __restrict__ counts, int E,
                                                         int histB,
                                                         const float* __restrict__ W1,
                                                         unsigned short* __restrict__ h1,
                                                         unsigned short* __restrict__ l1,
                                                         const float* __restrict__ W2,
                                                         unsigned short* __restrict__ h2,
                                                         unsigned short* __restrict__ l2) {
    int b = blockIdx.x;
    if (b < histB) {
        int e = b * 256 + threadIdx.x;
        if (e < E) atomicAdd(counts + dst[e], 1);
        return;
    }
    int tid = (b - histB) * 256 + threadIdx.x;
    if (tid < 128 * 256) {
        int k = tid >> 8, n = tid & 255;
        float f = W1[tid];
        unsigned short h = f2bf(f);
        h1[n * 128 + k] = h;
        l1[n * 128 + k] = f2bf(f - bf2f(h));
        return;
    }
    tid -= 128 * 256;
    if (tid < 256 * 64) {
        int k = tid >> 6, n = tid & 63;
        float f = W2[tid];
        unsigned short h = f2bf(f);
        h2[n * 256 + k] = h;
        l2[n * 256 + k] = f2bf(f - bf2f(h));
    }
}

// ---------- single-kernel exclusive scan (ticket + decoupled lookback) ----------
// counts[N] -> rowptr[N+1], cursor[N]=rowptr[i]. partial/tick pre-zeroed.
__global__ __launch_bounds__(256) void scan_kernel(const int* __restrict__ counts,
                                                   int* __restrict__ rowptr,
                                                   int* __restrict__ cursor,
                                                   unsigned long long* __restrict__ partial,
                                                   int* __restrict__ tick,
                                                   int N, int E, int NB) {
    __shared__ int sh[256];
    __shared__ int sbid, sexc;
    int tid = threadIdx.x;
    if (tid == 0) sbid = atomicAdd(tick, 1);
    __syncthreads();
    int bid = sbid;
    int i = bid * 256 + tid;
    int v = (i < N) ? counts[i] : 0;
    sh[tid] = v;
    __syncthreads();
    for (int off = 1; off < 256; off <<= 1) {
        int t = (tid >= off) ? sh[tid - off] : 0;
        __syncthreads();
        sh[tid] += t;
        __syncthreads();
    }
    int incl = sh[tid];
    int total = sh[255];
    if (tid == 0) {
        if (bid == 0) {
            __hip_atomic_store(&partial[0],
                               ((unsigned long long)(unsigned)total << 32) | 2ULL,
                               __ATOMIC_RELEASE, __HIP_MEMORY_SCOPE_AGENT);
            sexc = 0;
        } else {
            __hip_atomic_store(&partial[bid],
                               ((unsigned long long)(unsigned)total << 32) | 1ULL,
                               __ATOMIC_RELEASE, __HIP_MEMORY_SCOPE_AGENT);
            int exc = 0;
            for (int p = bid - 1; p >= 0; --p) {
                unsigned long long st;
                do {
                    st = __hip_atomic_load(&partial[p], __ATOMIC_ACQUIRE,
                                           __HIP_MEMORY_SCOPE_AGENT);
                } while ((st & 3ULL) == 0);
                exc += (int)(st >> 32);
                if (st & 2ULL) break;
            }
            __hip_atomic_store(&partial[bid],
                               ((unsigned long long)(unsigned)(exc + total) << 32) | 2ULL,
                               __ATOMIC_RELEASE, __HIP_MEMORY_SCOPE_AGENT);
            sexc = exc;
        }
    }
    __syncthreads();
    int exc = sexc;
    if (i < N) {
        int rp = exc + incl - v;   // exclusive
        rowptr[i] = rp;
        cursor[i] = rp;
    }
    if (bid == NB - 1 && tid == 255) rowptr[N] = E;
}

// ---------- MFMA GEMM body (device fn): C = A @ Wt^T, B hi/lo x2, el/er epilogue ----------
template<bool A_FP32>
__device__ __forceinline__ void gemm_body(int bx, int by,
                                          const void* __restrict__ A_any,
                                          const unsigned short* __restrict__ Bh_g,
                                          const unsigned short* __restrict__ Bl_g,
                                          unsigned short* __restrict__ C,
                                          const float* __restrict__ attn_l,
                                          const float* __restrict__ attn_r,
                                          float* __restrict__ el,
                                          float* __restrict__ er,
                                          int H, int M, int Nn, int K,
                                          unsigned short (*Ah)[136],
                                          unsigned short (*Bh)[136],
                                          unsigned short (*Bl)[136]) {
    int tid = threadIdx.x;
    int row0 = bx * 64;
    int col0 = by * 64;
    int wv = tid >> 6;
    int lane = tid & 63;
    int l15 = lane & 15;
    int kgrp = (lane >> 4) * 8;

    f32x4 acc[4] = {{0.f,0.f,0.f,0.f},{0.f,0.f,0.f,0.f},{0.f,0.f,0.f,0.f},{0.f,0.f,0.f,0.f}};

    for (int kc = 0; kc < K; kc += 128) {
        __syncthreads();
        #pragma unroll
        for (int p = 0; p < 4; p++) {
            int idx = (p * 256 + tid) * 8;
            int r = idx >> 7;
            int c = idx & 127;
            int gr = row0 + r;
            if (A_FP32) {
                const float* A = (const float*)A_any;
                float4 v0 = {0,0,0,0}, v1 = {0,0,0,0};
                if (gr < M) {
                    v0 = *(const float4*)(A + (size_t)gr * K + kc + c);
                    v1 = *(const float4*)(A + (size_t)gr * K + kc + c + 4);
                }
                ushort4 h0, h1;
                h0.x = f2bf(v0.x); h0.y = f2bf(v0.y);
                h0.z = f2bf(v0.z); h0.w = f2bf(v0.w);
                h1.x = f2bf(v1.x); h1.y = f2bf(v1.y);
                h1.z = f2bf(v1.z); h1.w = f2bf(v1.w);
                *(ushort4*)&Ah[r][c]     = h0;
                *(ushort4*)&Ah[r][c + 4] = h1;
            } else {
                const unsigned short* Ah_g = (const unsigned short*)A_any;
                uint4 vh = {0,0,0,0};
                if (gr < M) vh = *(const uint4*)(Ah_g + (size_t)gr * K + kc + c);
                *(uint4*)&Ah[r][c] = vh;
            }
            uint4 wh = *(const uint4*)(Bh_g + (size_t)(col0 + r) * K + kc + c);
            uint4 wl = *(const uint4*)(Bl_g + (size_t)(col0 + r) * K + kc + c);
            *(uint4*)&Bh[r][c] = wh;
            *(uint4*)&Bl[r][c] = wl;
        }
        __syncthreads();
        #pragma unroll
        for (int kk = 0; kk < 4; kk++) {
            int kc0 = kk * 32 + kgrp;
            short8v ah = *(short8v*)&Ah[wv * 16 + l15][kc0];
            #pragma unroll
            for (int c = 0; c < 4; c++) {
                short8v bh = *(short8v*)&Bh[c * 16 + l15][kc0];
                short8v bl = *(short8v*)&Bl[c * 16 + l15][kc0];
                acc[c] = __builtin_amdgcn_mfma_f32_16x16x32_bf16(ah, bh, acc[c], 0, 0, 0);
                acc[c] = __builtin_amdgcn_mfma_f32_16x16x32_bf16(ah, bl, acc[c], 0, 0, 0);
            }
        }
    }
    // C/D layout: col = lane&15, row = (lane>>4)*4 + j
    float elp[4] = {0.f, 0.f, 0.f, 0.f};
    float erp[4] = {0.f, 0.f, 0.f, 0.f};
    const float* alh = attn_l + by * 64;
    const float* arh = attn_r + by * 64;
    #pragma unroll
    for (int c = 0; c < 4; c++) {
        float av = alh[c * 16 + l15];
        float rv = arh[c * 16 + l15];
        #pragma unroll
        for (int j = 0; j < 4; j++) {
            int r = row0 + wv * 16 + (lane >> 4) * 4 + j;
            if (r < M) C[(size_t)r * Nn + col0 + c * 16 + l15] = f2bf(acc[c][j]);
            elp[j] += acc[c][j] * av;
            erp[j] += acc[c][j] * rv;
        }
    }
    #pragma unroll
    for (int j = 0; j < 4; j++) {
        #pragma unroll
        for (int off = 1; off < 16; off <<= 1) {
            elp[j] += __shfl_xor(elp[j], off);
            erp[j] += __shfl_xor(erp[j], off);
        }
    }
    if (l15 == 0) {
        #pragma unroll
        for (int j = 0; j < 4; j++) {
            int r = row0 + wv * 16 + (lane >> 4) * 4 + j;
            if (r < M) {
                el[(size_t)r * H + by] = elp[j];
                er[(size_t)r * H + by] = erp[j];
            }
        }
    }
}

// ---------- fused: gemm1 (blocks [0,gemmB)) + CSR fill (rest) ----------
__global__ __launch_bounds__(256) void gemm1_fill_kernel(const float* __restrict__ x,
                                                         const unsigned short* __restrict__ Bh_g,
                                                         const unsigned short* __restrict__ Bl_g,
                                                         unsigned short* __restrict__ C,
                                                         const float* __restrict__ attn_l,
                                                         const float* __restrict__ attn_r,
                                                         float* __restrict__ el,
                                                         float* __restrict__ er,
                                                         int M, int gemmB, int gx,
                                                         const int* __restrict__ src,
                                                         const int* __restrict__ dst,
                                                         int* __restrict__ cursor,
                                                         int* __restrict__ csr_src, int E) {
    __shared__ unsigned short Ah[64][136], Bh[64][136], Bl[64][136];
    int b = blockIdx.x;
    if (b < gemmB) {
        gemm_body<true>(b % gx, b / gx, x, Bh_g, Bl_g, C, attn_l, attn_r,
                        el, er, 4, M, 256, 128, Ah, Bh, Bl);
    } else {
        int e = (b - gemmB) * 256 + threadIdx.x;
        if (e < E) {
            int pos = atomicAdd(cursor + dst[e], 1);   // absolute position
            csr_src[pos] = src[e];
        }
    }
}

// ---------- gemm2 standalone ----------
__global__ __launch_bounds__(256) void gemm2_kernel(const unsigned short* __restrict__ A,
                                                    const unsigned short* __restrict__ Bh_g,
                                                    const unsigned short* __restrict__ Bl_g,
                                                    unsigned short* __restrict__ C,
                                                    const float* __restrict__ attn_l,
                                                    const float* __restrict__ attn_r,
                                                    float* __restrict__ el,
                                                    float* __restrict__ er, int M) {
    __shared__ unsigned short Ah[64][136], Bh[64][136], Bl[64][136];
    gemm_body<false>(blockIdx.x, 0, A, Bh_g, Bl_g, C, attn_l, attn_r,
                     el, er, 1, M, 64, 256, Ah, Bh, Bl);
}

// ---------- layer1 fused per-node, single-pass softmax, unroll x8/x4/tail ----------
__global__ __launch_bounds__(256) void gat1_node(const unsigned short* __restrict__ feat,
                                                 const float* __restrict__ el,
                                                 const float* __restrict__ er,
                                                 const int* __restrict__ rowptr,
                                                 const int* __restrict__ csr_src,
                                                 const float* __restrict__ bias,
                                                 unsigned short* __restrict__ out_h, int N) {
    int node = (blockIdx.x * 256 + threadIdx.x) >> 6;
    int lane = threadIdx.x & 63;
    if (node >= N) return;
    int h = lane >> 4;
    int beg = rowptr[node], end = rowptr[node + 1];
    float erd = er[(size_t)node * 4 + h];
    float den = 0.f;
    float4 acc = {0.f, 0.f, 0.f, 0.f};
    int k = beg;
    for (; k + 7 < end; k += 8) {
        int s[8];
        #pragma unroll
        for (int u = 0; u < 8; u++) s[u] = csr_src[k + u];
        float e[8];
        #pragma unroll
        for (int u = 0; u < 8; u++) e[u] = el[(size_t)s[u] * 4 + h];
        ushort4 f[8];
        #pragma unroll
        for (int u = 0; u < 8; u++)
            f[u] = *(const ushort4*)(feat + (size_t)s[u] * 256 + lane * 4);
        #pragma unroll
        for (int u = 0; u < 8; u++) {
            float sc = e[u] + erd;
            sc = sc > 0.f ? sc : NEG_SLOPE * sc;
            float w = __expf(sc);
            den += w;
            acc.x += w * bf2f(f[u].x);
            acc.y += w * bf2f(f[u].y);
            acc.z += w * bf2f(f[u].z);
            acc.w += w * bf2f(f[u].w);
        }
    }
    for (; k + 3 < end; k += 4) {
        int s[4];
        #pragma unroll
        for (int u = 0; u < 4; u++) s[u] = csr_src[k + u];
        float e[4];
        #pragma unroll
        for (int u = 0; u < 4; u++) e[u] = el[(size_t)s[u] * 4 + h];
        ushort4 f[4];
        #pragma unroll
        for (int u = 0; u < 4; u++)
            f[u] = *(const ushort4*)(feat + (size_t)s[u] * 256 + lane * 4);
        #pragma unroll
        for (int u = 0; u < 4; u++) {
            float sc = e[u] + erd;
            sc = sc > 0.f ? sc : NEG_SLOPE * sc;
            float w = __expf(sc);
            den += w;
            acc.x += w * bf2f(f[u].x);
            acc.y += w * bf2f(f[u].y);
            acc.z += w * bf2f(f[u].z);
            acc.w += w * bf2f(f[u].w);
        }
    }
    for (; k < end; k++) {
        int s = csr_src[k];
        float sc = el[(size_t)s * 4 + h] + erd;
        sc = sc > 0.f ? sc : NEG_SLOPE * sc;
        float w = __expf(sc);
        ushort4 f = *(const ushort4*)(feat + (size_t)s * 256 + lane * 4);
        den += w;
        acc.x += w * bf2f(f.x);
        acc.y += w * bf2f(f.y);
        acc.z += w * bf2f(f.z);
        acc.w += w * bf2f(f.w);
    }
    float inv = (den > 0.f) ? 1.f / den : 0.f;
    float4 b = *(const float4*)(bias + lane * 4);
    ushort4 oh;
    oh.x = f2bf(fmaxf(acc.x * inv + b.x, 0.f));
    oh.y = f2bf(fmaxf(acc.y * inv + b.y, 0.f));
    oh.z = f2bf(fmaxf(acc.z * inv + b.z, 0.f));
    oh.w = f2bf(fmaxf(acc.w * inv + b.w, 0.f));
    *(ushort4*)(out_h + (size_t)node * 256 + lane * 4) = oh;
}

// ---------- layer2 fused per-node, single-pass + bias + relu + row-sum ----------
__global__ __launch_bounds__(256) void gat2_node(const unsigned short* __restrict__ feat,
                                                 const float* __restrict__ el,
                                                 const float* __restrict__ er,
                                                 const int* __restrict__ rowptr,
                                                 const int* __restrict__ csr_src,
                                                 const float* __restrict__ bias,
                                                 float* __restrict__ emb,
                                                 float* __restrict__ go, int N) {
    int node = (blockIdx.x * 256 + threadIdx.x) >> 6;
    int lane = threadIdx.x & 63;
    if (node >= N) return;
    int beg = rowptr[node], end = rowptr[node + 1];
    float erd = er[node];
    float den = 0.f, acc = 0.f;
    int k = beg;
    for (; k + 7 < end; k += 8) {
        int s[8];
        #pragma unroll
        for (int u = 0; u < 8; u++) s[u] = csr_src[k + u];
        float e[8];
        #pragma unroll
        for (int u = 0; u < 8; u++) e[u] = el[s[u]];
        unsigned short f[8];
        #pragma unroll
        for (int u = 0; u < 8; u++) f[u] = feat[(size_t)s[u] * 64 + lane];
        #pragma unroll
        for (int u = 0; u < 8; u++) {
            float sc = e[u] + erd;
            sc = sc > 0.f ? sc : NEG_SLOPE * sc;
            float w = __expf(sc);
            den += w;
            acc += w * bf2f(f[u]);
        }
    }
    for (; k + 3 < end; k += 4) {
        int s[4];
        #pragma unroll
        for (int u = 0; u < 4; u++) s[u] = csr_src[k + u];
        float e[4];
        #pragma unroll
        for (int u = 0; u < 4; u++) e[u] = el[s[u]];
        unsigned short f[4];
        #pragma unroll
        for (int u = 0; u < 4; u++) f[u] = feat[(size_t)s[u] * 64 + lane];
        #pragma unroll
        for (int u = 0; u < 4; u++) {
            float sc = e[u] + erd;
            sc = sc > 0.f ? sc : NEG_SLOPE * sc;
            float w = __expf(sc);
            den += w;
            acc += w * bf2f(f[u]);
        }
    }
    for (; k < end; k++) {
        int s = csr_src[k];
        float sc = el[s] + erd;
        sc = sc > 0.f ? sc : NEG_SLOPE * sc;
        float w = __expf(sc);
        den += w;
        acc += w * bf2f(feat[(size_t)s * 64 + lane]);
    }
    float inv = (den > 0.f) ? 1.f / den : 0.f;
    float v = fmaxf(acc * inv + bias[lane], 0.f);
    go[(size_t)node * 64 + lane] = v;
    float sum = v;
    #pragma unroll
    for (int off = 1; off < 64; off <<= 1) sum += __shfl_xor(sum, off);
    if (lane == 0) emb[node] = sum;
}

extern "C" void kernel_launch(void* const* d_in, const int* in_sizes, int n_in,
                              void* d_out, int out_size, void* d_ws, size_t ws_size,
                              hipStream_t stream) {
    const float* x   = (const float*)d_in[0];
    const int*   src = (const int*)d_in[1];
    const int*   dst = (const int*)d_in[2];
    const float* W1  = (const float*)d_in[3];
    const float* al1 = (const float*)d_in[4];
    const float* ar1 = (const float*)d_in[5];
    const float* b1  = (const float*)d_in[6];
    const float* W2  = (const float*)d_in[7];
    const float* al2 = (const float*)d_in[8];
    const float* ar2 = (const float*)d_in[9];
    const float* b2  = (const float*)d_in[10];
    const int N = in_sizes[0] / 128;
    const int E = in_sizes[1];
    const int NB = (N + 255) / 256;

    char* base = (char*)d_ws;
    size_t off = 0;
    auto alloc = [&](size_t bytes) {
        off = (off + 255) & ~(size_t)255;
        void* p = base + off;
        off += bytes;
        return p;
    };
    unsigned short* feat1 = (unsigned short*)alloc((size_t)N * 256 * 2);
    unsigned short* feat2 = (unsigned short*)alloc((size_t)N * 64 * 2);
    float* el1   = (float*)alloc((size_t)N * 4 * 4);
    float* er1   = (float*)alloc((size_t)N * 4 * 4);
    float* el2   = (float*)alloc((size_t)N * 4);
    float* er2   = (float*)alloc((size_t)N * 4);
    // --- zero region: counts + partial + tick (one memset) ---
    int* icounts = (int*)alloc((size_t)N * 4);
    unsigned long long* partial = (unsigned long long*)alloc((size_t)NB * 8);
    int* tick = (int*)alloc(4);
    size_t zbytes = (size_t)((char*)tick + 4 - (char*)icounts);
    // --- end zero region ---
    int* icursor = (int*)alloc((size_t)N * 4);
    int* irowp   = (int*)alloc((size_t)(N + 1) * 4);
    int* icsrs   = (int*)alloc((size_t)E * 4);
    unsigned short* w1th = (unsigned short*)alloc((size_t)128 * 256 * 2);
    unsigned short* w1tl = (unsigned short*)alloc((size_t)128 * 256 * 2);
    unsigned short* hh   = (unsigned short*)alloc((size_t)N * 256 * 2);
    unsigned short* w2th = (unsigned short*)alloc((size_t)256 * 64 * 2);
    unsigned short* w2tl = (unsigned short*)alloc((size_t)256 * 64 * 2);
    (void)ws_size;

    // 1. zero counts/partial/tick
    hipMemsetAsync(icounts, 0, zbytes, stream);

    // 2. hist + weight split (fused)
    {
        int histB = (E + 255) / 256;
        int splitB = (128 * 256 + 256 * 64 + 255) / 256;
        hist_split_kernel<<<histB + splitB, 256, 0, stream>>>(
            dst, icounts, E, histB, W1, w1th, w1tl, W2, w2th, w2tl);
    }

    // 3. single-kernel scan -> rowptr + cursor
    scan_kernel<<<NB, 256, 0, stream>>>(icounts, irowp, icursor, partial, tick, N, E, NB);

    // 4. gemm1 (x @ W1 + el/er epilogue) || CSR fill (fused)
    {
        int gx = (N + 63) / 64;
        int gemmB = gx * 4;
        int fillB = (E + 255) / 256;
        gemm1_fill_kernel<<<gemmB + fillB, 256, 0, stream>>>(
            x, w1th, w1tl, feat1, al1, ar1, el1, er1, N, gemmB, gx,
            src, dst, icursor, icsrs, E);
    }

    // 5. layer-1 attention aggregate
    gat1_node<<<(N + 3) / 4, 256, 0, stream>>>(feat1, el1, er1, irowp, icsrs, b1, hh, N);

    // 6. gemm2 (h @ W2 + el/er epilogue)
    gemm2_kernel<<<(N + 63) / 64, 256, 0, stream>>>(hh, w2th, w2tl, feat2,
                                                    al2, ar2, el2, er2, N);

    // 7. layer-2 attention aggregate + bias + relu + row-sum
    gat2_node<<<(N + 3) / 4, 256, 0, stream>>>(feat2, el2, er2, irowp, icsrs, b2,
                                               (float*)d_out, (float*)d_out + N, N);
}

// Round 10
// 274.458 us; speedup vs baseline: 1.0068x; 1.0068x over previous
//
#include <hip/hip_runtime.h>
#include <hip/hip_bf16.h>

#define NEG_SLOPE 0.2f

typedef __attribute__((ext_vector_type(8))) short short8v;
typedef __attribute__((ext_vector_type(4))) float f32x4;

// ---------- bf16 round-to-nearest helpers ----------
__device__ __forceinline__ unsigned short f2bf(float f) {
    unsigned u = __float_as_uint(f);
    unsigned r = (u + 0x7FFFu + ((u >> 16) & 1u)) >> 16;
    return (unsigned short)r;
}
__device__ __forceinline__ float bf2f(unsigned short h) {
    return __uint_as_float((unsigned)h << 16);
}

// ---------- fused: histogram + weight split/transpose ----------
__global__ __launch_bounds__(256) void hist_split_kernel(const int* __restrict__ dst,
                                                         int* __restrict__ counts, int E,
                                                         int histB,
                                                         const float* __restrict__ W1,
                                                         unsigned short* __restrict__ h1,
                                                         unsigned short* __restrict__ l1,
                                                         const float* __restrict__ W2,
                                                         unsigned short* __restrict__ h2,
                                                         unsigned short* __restrict__ l2) {
    int b = blockIdx.x;
    if (b < histB) {
        int e = b * 256 + threadIdx.x;
        if (e < E) atomicAdd(counts + dst[e], 1);
        return;
    }
    int tid = (b - histB) * 256 + threadIdx.x;
    if (tid < 128 * 256) {
        int k = tid >> 8, n = tid & 255;
        float f = W1[tid];
        unsigned short h = f2bf(f);
        h1[n * 128 + k] = h;
        l1[n * 128 + k] = f2bf(f - bf2f(h));
        return;
    }
    tid -= 128 * 256;
    if (tid < 256 * 64) {
        int k = tid >> 6, n = tid & 63;
        float f = W2[tid];
        unsigned short h = f2bf(f);
        h2[n * 256 + k] = h;
        l2[n * 256 + k] = f2bf(f - bf2f(h));
    }
}

// ---------- single-kernel exclusive scan (ticket + decoupled lookback) ----------
__global__ __launch_bounds__(256) void scan_kernel(const int* __restrict__ counts,
                                                   int* __restrict__ rowptr,
                                                   int* __restrict__ cursor,
                                                   unsigned long long* __restrict__ partial,
                                                   int* __restrict__ tick,
                                                   int N, int E, int NB) {
    __shared__ int sh[256];
    __shared__ int sbid, sexc;
    int tid = threadIdx.x;
    if (tid == 0) sbid = atomicAdd(tick, 1);
    __syncthreads();
    int bid = sbid;
    int i = bid * 256 + tid;
    int v = (i < N) ? counts[i] : 0;
    sh[tid] = v;
    __syncthreads();
    for (int off = 1; off < 256; off <<= 1) {
        int t = (tid >= off) ? sh[tid - off] : 0;
        __syncthreads();
        sh[tid] += t;
        __syncthreads();
    }
    int incl = sh[tid];
    int total = sh[255];
    if (tid == 0) {
        if (bid == 0) {
            __hip_atomic_store(&partial[0],
                               ((unsigned long long)(unsigned)total << 32) | 2ULL,
                               __ATOMIC_RELEASE, __HIP_MEMORY_SCOPE_AGENT);
            sexc = 0;
        } else {
            __hip_atomic_store(&partial[bid],
                               ((unsigned long long)(unsigned)total << 32) | 1ULL,
                               __ATOMIC_RELEASE, __HIP_MEMORY_SCOPE_AGENT);
            int exc = 0;
            for (int p = bid - 1; p >= 0; --p) {
                unsigned long long st;
                do {
                    st = __hip_atomic_load(&partial[p], __ATOMIC_ACQUIRE,
                                           __HIP_MEMORY_SCOPE_AGENT);
                } while ((st & 3ULL) == 0);
                exc += (int)(st >> 32);
                if (st & 2ULL) break;
            }
            __hip_atomic_store(&partial[bid],
                               ((unsigned long long)(unsigned)(exc + total) << 32) | 2ULL,
                               __ATOMIC_RELEASE, __HIP_MEMORY_SCOPE_AGENT);
            sexc = exc;
        }
    }
    __syncthreads();
    int exc = sexc;
    if (i < N) {
        int rp = exc + incl - v;   // exclusive
        rowptr[i] = rp;
        cursor[i] = rp;
    }
    if (bid == NB - 1 && tid == 255) rowptr[N] = E;
}

// ---------- CSR fill (standalone, no LDS -> full occupancy) ----------
__global__ __launch_bounds__(256) void fill_kernel(const int* __restrict__ src,
                                                   const int* __restrict__ dst,
                                                   int* __restrict__ cursor,
                                                   int* __restrict__ csr_src, int E) {
    int e = blockIdx.x * 256 + threadIdx.x;
    if (e >= E) return;
    int pos = atomicAdd(cursor + dst[e], 1);   // absolute position
    csr_src[pos] = src[e];
}

// ---------- streaming MFMA GEMM: weights resident in LDS, A global->reg ----------
// C[M, NHEAD*64](bf16) = A[M,K] @ Wt[NHEAD*64, K]^T  via B hi/lo x2 MFMA.
// grid (M/64, NHEAD); block 256 = 4 waves; wave w -> rows w*16..+15 of the
// block's 64 rows; all 64 cols of head blockIdx.y. One sync total.
// Epilogue: el/er fused (fp32 accumulator precision).
template<bool A_FP32, int K, int NHEAD>
__global__ __launch_bounds__(256) void gemm_stream(const void* __restrict__ A_any,
                                                   const unsigned short* __restrict__ BhT,
                                                   const unsigned short* __restrict__ BlT,
                                                   unsigned short* __restrict__ C,
                                                   const float* __restrict__ attn_l,
                                                   const float* __restrict__ attn_r,
                                                   float* __restrict__ el,
                                                   float* __restrict__ er, int M) {
    constexpr int KW = K + 8;          // +16B pad per row
    constexpr int Nn = NHEAD * 64;
    __shared__ unsigned short Bh[64][KW], Bl[64][KW];
    int hy = blockIdx.y;
    int row0 = blockIdx.x * 64;
    int tid = threadIdx.x;
    int wv = tid >> 6, lane = tid & 63, l15 = lane & 15, g8 = (lane >> 4) * 8;

    // stage this head's weight slice (contiguous 64*K bf16 per h/l)
    const unsigned short* sh_ = BhT + (size_t)hy * 64 * K;
    const unsigned short* sl_ = BlT + (size_t)hy * 64 * K;
    for (int idx = tid; idx < 64 * K / 8; idx += 256) {
        int r = idx / (K / 8), c = (idx % (K / 8)) * 8;
        *(uint4*)&Bh[r][c] = *(const uint4*)(sh_ + r * K + c);
        *(uint4*)&Bl[r][c] = *(const uint4*)(sl_ + r * K + c);
    }
    __syncthreads();

    int arow = row0 + wv * 16 + l15;
    bool rok = arow < M;
    f32x4 acc[4] = {{0.f,0.f,0.f,0.f},{0.f,0.f,0.f,0.f},{0.f,0.f,0.f,0.f},{0.f,0.f,0.f,0.f}};

    #pragma unroll
    for (int kk = 0; kk < K / 32; kk++) {
        short8v ah;
        if (A_FP32) {
            const float* A = (const float*)A_any;
            float4 v0 = {0,0,0,0}, v1 = {0,0,0,0};
            if (rok) {
                v0 = *(const float4*)(A + (size_t)arow * K + kk * 32 + g8);
                v1 = *(const float4*)(A + (size_t)arow * K + kk * 32 + g8 + 4);
            }
            union { unsigned short u[8]; short8v v; } cv;
            cv.u[0] = f2bf(v0.x); cv.u[1] = f2bf(v0.y);
            cv.u[2] = f2bf(v0.z); cv.u[3] = f2bf(v0.w);
            cv.u[4] = f2bf(v1.x); cv.u[5] = f2bf(v1.y);
            cv.u[6] = f2bf(v1.z); cv.u[7] = f2bf(v1.w);
            ah = cv.v;
        } else {
            const unsigned short* A = (const unsigned short*)A_any;
            uint4 raw = {0,0,0,0};
            if (rok) raw = *(const uint4*)(A + (size_t)arow * K + kk * 32 + g8);
            ah = *(short8v*)&raw;
        }
        #pragma unroll
        for (int c = 0; c < 4; c++) {
            short8v bh = *(short8v*)&Bh[c * 16 + l15][kk * 32 + g8];
            short8v bl = *(short8v*)&Bl[c * 16 + l15][kk * 32 + g8];
            acc[c] = __builtin_amdgcn_mfma_f32_16x16x32_bf16(ah, bh, acc[c], 0, 0, 0);
            acc[c] = __builtin_amdgcn_mfma_f32_16x16x32_bf16(ah, bl, acc[c], 0, 0, 0);
        }
    }

    // C/D layout: col = lane&15, row = (lane>>4)*4 + j
    float elp[4] = {0.f, 0.f, 0.f, 0.f};
    float erp[4] = {0.f, 0.f, 0.f, 0.f};
    const float* alh = attn_l + hy * 64;
    const float* arh = attn_r + hy * 64;
    int col0 = hy * 64;
    #pragma unroll
    for (int c = 0; c < 4; c++) {
        float av = alh[c * 16 + l15];
        float rv = arh[c * 16 + l15];
        #pragma unroll
        for (int j = 0; j < 4; j++) {
            int r = row0 + wv * 16 + (lane >> 4) * 4 + j;
            if (r < M) C[(size_t)r * Nn + col0 + c * 16 + l15] = f2bf(acc[c][j]);
            elp[j] += acc[c][j] * av;
            erp[j] += acc[c][j] * rv;
        }
    }
    #pragma unroll
    for (int j = 0; j < 4; j++) {
        #pragma unroll
        for (int off = 1; off < 16; off <<= 1) {
            elp[j] += __shfl_xor(elp[j], off);
            erp[j] += __shfl_xor(erp[j], off);
        }
    }
    if (l15 == 0) {
        #pragma unroll
        for (int j = 0; j < 4; j++) {
            int r = row0 + wv * 16 + (lane >> 4) * 4 + j;
            if (r < M) {
                el[(size_t)r * NHEAD + hy] = elp[j];
                er[(size_t)r * NHEAD + hy] = erp[j];
            }
        }
    }
}

// ---------- layer1 fused per-node, single-pass softmax, unroll x8/x4/tail ----------
__global__ __launch_bounds__(256) void gat1_node(const unsigned short* __restrict__ feat,
                                                 const float* __restrict__ el,
                                                 const float* __restrict__ er,
                                                 const int* __restrict__ rowptr,
                                                 const int* __restrict__ csr_src,
                                                 const float* __restrict__ bias,
                                                 unsigned short* __restrict__ out_h, int N) {
    int node = (blockIdx.x * 256 + threadIdx.x) >> 6;
    int lane = threadIdx.x & 63;
    if (node >= N) return;
    int h = lane >> 4;
    int beg = rowptr[node], end = rowptr[node + 1];
    float erd = er[(size_t)node * 4 + h];
    float den = 0.f;
    float4 acc = {0.f, 0.f, 0.f, 0.f};
    int k = beg;
    for (; k + 7 < end; k += 8) {
        int s[8];
        #pragma unroll
        for (int u = 0; u < 8; u++) s[u] = csr_src[k + u];
        float e[8];
        #pragma unroll
        for (int u = 0; u < 8; u++) e[u] = el[(size_t)s[u] * 4 + h];
        ushort4 f[8];
        #pragma unroll
        for (int u = 0; u < 8; u++)
            f[u] = *(const ushort4*)(feat + (size_t)s[u] * 256 + lane * 4);
        #pragma unroll
        for (int u = 0; u < 8; u++) {
            float sc = e[u] + erd;
            sc = sc > 0.f ? sc : NEG_SLOPE * sc;
            float w = __expf(sc);
            den += w;
            acc.x += w * bf2f(f[u].x);
            acc.y += w * bf2f(f[u].y);
            acc.z += w * bf2f(f[u].z);
            acc.w += w * bf2f(f[u].w);
        }
    }
    for (; k + 3 < end; k += 4) {
        int s[4];
        #pragma unroll
        for (int u = 0; u < 4; u++) s[u] = csr_src[k + u];
        float e[4];
        #pragma unroll
        for (int u = 0; u < 4; u++) e[u] = el[(size_t)s[u] * 4 + h];
        ushort4 f[4];
        #pragma unroll
        for (int u = 0; u < 4; u++)
            f[u] = *(const ushort4*)(feat + (size_t)s[u] * 256 + lane * 4);
        #pragma unroll
        for (int u = 0; u < 4; u++) {
            float sc = e[u] + erd;
            sc = sc > 0.f ? sc : NEG_SLOPE * sc;
            float w = __expf(sc);
            den += w;
            acc.x += w * bf2f(f[u].x);
            acc.y += w * bf2f(f[u].y);
            acc.z += w * bf2f(f[u].z);
            acc.w += w * bf2f(f[u].w);
        }
    }
    for (; k < end; k++) {
        int s = csr_src[k];
        float sc = el[(size_t)s * 4 + h] + erd;
        sc = sc > 0.f ? sc : NEG_SLOPE * sc;
        float w = __expf(sc);
        ushort4 f = *(const ushort4*)(feat + (size_t)s * 256 + lane * 4);
        den += w;
        acc.x += w * bf2f(f.x);
        acc.y += w * bf2f(f.y);
        acc.z += w * bf2f(f.z);
        acc.w += w * bf2f(f.w);
    }
    float inv = (den > 0.f) ? 1.f / den : 0.f;
    float4 b = *(const float4*)(bias + lane * 4);
    ushort4 oh;
    oh.x = f2bf(fmaxf(acc.x * inv + b.x, 0.f));
    oh.y = f2bf(fmaxf(acc.y * inv + b.y, 0.f));
    oh.z = f2bf(fmaxf(acc.z * inv + b.z, 0.f));
    oh.w = f2bf(fmaxf(acc.w * inv + b.w, 0.f));
    *(ushort4*)(out_h + (size_t)node * 256 + lane * 4) = oh;
}

// ---------- layer2 fused per-node, single-pass + bias + relu + row-sum ----------
__global__ __launch_bounds__(256) void gat2_node(const unsigned short* __restrict__ feat,
                                                 const float* __restrict__ el,
                                                 const float* __restrict__ er,
                                                 const int* __restrict__ rowptr,
                                                 const int* __restrict__ csr_src,
                                                 const float* __restrict__ bias,
                                                 float* __restrict__ emb,
                                                 float* __restrict__ go, int N) {
    int node = (blockIdx.x * 256 + threadIdx.x) >> 6;
    int lane = threadIdx.x & 63;
    if (node >= N) return;
    int beg = rowptr[node], end = rowptr[node + 1];
    float erd = er[node];
    float den = 0.f, acc = 0.f;
    int k = beg;
    for (; k + 7 < end; k += 8) {
        int s[8];
        #pragma unroll
        for (int u = 0; u < 8; u++) s[u] = csr_src[k + u];
        float e[8];
        #pragma unroll
        for (int u = 0; u < 8; u++) e[u] = el[s[u]];
        unsigned short f[8];
        #pragma unroll
        for (int u = 0; u < 8; u++) f[u] = feat[(size_t)s[u] * 64 + lane];
        #pragma unroll
        for (int u = 0; u < 8; u++) {
            float sc = e[u] + erd;
            sc = sc > 0.f ? sc : NEG_SLOPE * sc;
            float w = __expf(sc);
            den += w;
            acc += w * bf2f(f[u]);
        }
    }
    for (; k + 3 < end; k += 4) {
        int s[4];
        #pragma unroll
        for (int u = 0; u < 4; u++) s[u] = csr_src[k + u];
        float e[4];
        #pragma unroll
        for (int u = 0; u < 4; u++) e[u] = el[s[u]];
        unsigned short f[4];
        #pragma unroll
        for (int u = 0; u < 4; u++) f[u] = feat[(size_t)s[u] * 64 + lane];
        #pragma unroll
        for (int u = 0; u < 4; u++) {
            float sc = e[u] + erd;
            sc = sc > 0.f ? sc : NEG_SLOPE * sc;
            float w = __expf(sc);
            den += w;
            acc += w * bf2f(f[u]);
        }
    }
    for (; k < end; k++) {
        int s = csr_src[k];
        float sc = el[s] + erd;
        sc = sc > 0.f ? sc : NEG_SLOPE * sc;
        float w = __expf(sc);
        den += w;
        acc += w * bf2f(feat[(size_t)s * 64 + lane]);
    }
    float inv = (den > 0.f) ? 1.f / den : 0.f;
    float v = fmaxf(acc * inv + bias[lane], 0.f);
    go[(size_t)node * 64 + lane] = v;
    float sum = v;
    #pragma unroll
    for (int off = 1; off < 64; off <<= 1) sum += __shfl_xor(sum, off);
    if (lane == 0) emb[node] = sum;
}

extern "C" void kernel_launch(void* const* d_in, const int* in_sizes, int n_in,
                              void* d_out, int out_size, void* d_ws, size_t ws_size,
                              hipStream_t stream) {
    const float* x   = (const float*)d_in[0];
    const int*   src = (const int*)d_in[1];
    const int*   dst = (const int*)d_in[2];
    const float* W1  = (const float*)d_in[3];
    const float* al1 = (const float*)d_in[4];
    const float* ar1 = (const float*)d_in[5];
    const float* b1  = (const float*)d_in[6];
    const float* W2  = (const float*)d_in[7];
    const float* al2 = (const float*)d_in[8];
    const float* ar2 = (const float*)d_in[9];
    const float* b2  = (const float*)d_in[10];
    const int N = in_sizes[0] / 128;
    const int E = in_sizes[1];
    const int NB = (N + 255) / 256;

    char* base = (char*)d_ws;
    size_t off = 0;
    auto alloc = [&](size_t bytes) {
        off = (off + 255) & ~(size_t)255;
        void* p = base + off;
        off += bytes;
        return p;
    };
    unsigned short* feat1 = (unsigned short*)alloc((size_t)N * 256 * 2);
    unsigned short* feat2 = (unsigned short*)alloc((size_t)N * 64 * 2);
    float* el1   = (float*)alloc((size_t)N * 4 * 4);
    float* er1   = (float*)alloc((size_t)N * 4 * 4);
    float* el2   = (float*)alloc((size_t)N * 4);
    float* er2   = (float*)alloc((size_t)N * 4);
    // --- zero region: counts + partial + tick (one memset) ---
    int* icounts = (int*)alloc((size_t)N * 4);
    unsigned long long* partial = (unsigned long long*)alloc((size_t)NB * 8);
    int* tick = (int*)alloc(4);
    size_t zbytes = (size_t)((char*)tick + 4 - (char*)icounts);
    // --- end zero region ---
    int* icursor = (int*)alloc((size_t)N * 4);
    int* irowp   = (int*)alloc((size_t)(N + 1) * 4);
    int* icsrs   = (int*)alloc((size_t)E * 4);
    unsigned short* w1th = (unsigned short*)alloc((size_t)128 * 256 * 2);
    unsigned short* w1tl = (unsigned short*)alloc((size_t)128 * 256 * 2);
    unsigned short* hh   = (unsigned short*)alloc((size_t)N * 256 * 2);
    unsigned short* w2th = (unsigned short*)alloc((size_t)256 * 64 * 2);
    unsigned short* w2tl = (unsigned short*)alloc((size_t)256 * 64 * 2);
    (void)ws_size;

    // 1. zero counts/partial/tick
    hipMemsetAsync(icounts, 0, zbytes, stream);

    // 2. hist + weight split (fused)
    {
        int histB = (E + 255) / 256;
        int splitB = (128 * 256 + 256 * 64 + 255) / 256;
        hist_split_kernel<<<histB + splitB, 256, 0, stream>>>(
            dst, icounts, E, histB, W1, w1th, w1tl, W2, w2th, w2tl);
    }

    // 3. single-kernel scan -> rowptr + cursor
    scan_kernel<<<NB, 256, 0, stream>>>(icounts, irowp, icursor, partial, tick, N, E, NB);

    // 4. CSR fill (standalone, full occupancy)
    fill_kernel<<<(E + 255) / 256, 256, 0, stream>>>(src, dst, icursor, icsrs, E);

    // 5. gemm1: x @ W1 (+ el/er epilogue), weights-in-LDS streaming
    {
        dim3 g((N + 63) / 64, 4);
        gemm_stream<true, 128, 4><<<g, 256, 0, stream>>>(x, w1th, w1tl, feat1,
                                                         al1, ar1, el1, er1, N);
    }

    // 6. layer-1 attention aggregate
    gat1_node<<<(N + 3) / 4, 256, 0, stream>>>(feat1, el1, er1, irowp, icsrs, b1, hh, N);

    // 7. gemm2: h @ W2 (+ el/er epilogue)
    {
        dim3 g((N + 63) / 64, 1);
        gemm_stream<false, 256, 1><<<g, 256, 0, stream>>>(hh, w2th, w2tl, feat2,
                                                          al2, ar2, el2, er2, N);
    }

    // 8. layer-2 attention aggregate + bias + relu + row-sum
    gat2_node<<<(N + 3) / 4, 256, 0, stream>>>(feat2, el2, er2, irowp, icsrs, b2,
                                               (float*)d_out, (float*)d_out + N, N);
}

// Round 11
// 243.787 us; speedup vs baseline: 1.1335x; 1.1258x over previous
//
#include <hip/hip_runtime.h>
#include <hip/hip_bf16.h>

#define NEG_SLOPE 0.2f

typedef __attribute__((ext_vector_type(8))) short short8v;
typedef __attribute__((ext_vector_type(4))) float f32x4;

// ---------- bf16 round-to-nearest helpers ----------
__device__ __forceinline__ unsigned short f2bf(float f) {
    unsigned u = __float_as_uint(f);
    unsigned r = (u + 0x7FFFu + ((u >> 16) & 1u)) >> 16;
    return (unsigned short)r;
}
__device__ __forceinline__ float bf2f(unsigned short h) {
    return __uint_as_float((unsigned)h << 16);
}

// ---------- fused: histogram + weight split/transpose ----------
__global__ __launch_bounds__(256) void hist_split_kernel(const int* __restrict__ dst,
                                                         int* __restrict__ counts, int E,
                                                         int histB,
                                                         const float* __restrict__ W1,
                                                         unsigned short* __restrict__ h1,
                                                         unsigned short* __restrict__ l1,
                                                         const float* __restrict__ W2,
                                                         unsigned short* __restrict__ h2,
                                                         unsigned short* __restrict__ l2) {
    int b = blockIdx.x;
    if (b < histB) {
        int e = b * 256 + threadIdx.x;
        if (e < E) atomicAdd(counts + dst[e], 1);
        return;
    }
    int tid = (b - histB) * 256 + threadIdx.x;
    if (tid < 128 * 256) {
        int k = tid >> 8, n = tid & 255;
        float f = W1[tid];
        unsigned short h = f2bf(f);
        h1[n * 128 + k] = h;
        l1[n * 128 + k] = f2bf(f - bf2f(h));
        return;
    }
    tid -= 128 * 256;
    if (tid < 256 * 64) {
        int k = tid >> 6, n = tid & 63;
        float f = W2[tid];
        unsigned short h = f2bf(f);
        h2[n * 256 + k] = h;
        l2[n * 256 + k] = f2bf(f - bf2f(h));
    }
}

// ---------- CSR scan: per-block sums ----------
__global__ __launch_bounds__(256) void bsum_kernel(const int* __restrict__ counts,
                                                   int* __restrict__ bsum, int N) {
    __shared__ int sh[256];
    int i = blockIdx.x * 256 + threadIdx.x;
    int v = (i < N) ? counts[i] : 0;
    sh[threadIdx.x] = v;
    __syncthreads();
    for (int off = 128; off > 0; off >>= 1) {
        if (threadIdx.x < off) sh[threadIdx.x] += sh[threadIdx.x + off];
        __syncthreads();
    }
    if (threadIdx.x == 0) bsum[blockIdx.x] = sh[0];
}

// ---------- CSR scan: scan block sums (single block) ----------
__global__ __launch_bounds__(256) void bscan_kernel(int* __restrict__ bsum, int nb,
                                                    int* __restrict__ rowptr, int N, int E) {
    __shared__ int sh[256];
    int tid = threadIdx.x;
    int carry = 0;
    for (int base = 0; base < nb; base += 256) {
        int i = base + tid;
        int v = (i < nb) ? bsum[i] : 0;
        sh[tid] = v;
        __syncthreads();
        for (int off = 1; off < 256; off <<= 1) {
            int t = (tid >= off) ? sh[tid - off] : 0;
            __syncthreads();
            sh[tid] += t;
            __syncthreads();
        }
        if (i < nb) bsum[i] = carry + sh[tid] - v;  // exclusive
        int tot = sh[255];
        __syncthreads();
        carry += tot;
    }
    if (tid == 0) rowptr[N] = E;
}

// ---------- CSR scan: per-block scan + offset -> rowptr, cursor=rowptr ----------
__global__ __launch_bounds__(256) void rowptr_kernel(const int* __restrict__ counts,
                                                     const int* __restrict__ bsum,
                                                     int* __restrict__ rowptr,
                                                     int* __restrict__ cursor, int N) {
    __shared__ int sh[256];
    int i = blockIdx.x * 256 + threadIdx.x;
    int tid = threadIdx.x;
    int v = (i < N) ? counts[i] : 0;
    sh[tid] = v;
    __syncthreads();
    for (int off = 1; off < 256; off <<= 1) {
        int t = (tid >= off) ? sh[tid - off] : 0;
        __syncthreads();
        sh[tid] += t;
        __syncthreads();
    }
    if (i < N) {
        int rp = bsum[blockIdx.x] + sh[tid] - v;  // exclusive
        rowptr[i] = rp;
        cursor[i] = rp;
    }
}

// ---------- CSR fill ----------
__global__ __launch_bounds__(256) void fill_kernel(const int* __restrict__ src,
                                                   const int* __restrict__ dst,
                                                   int* __restrict__ cursor,
                                                   int* __restrict__ csr_src, int E) {
    int e = blockIdx.x * 256 + threadIdx.x;
    if (e >= E) return;
    int pos = atomicAdd(cursor + dst[e], 1);   // absolute position
    csr_src[pos] = src[e];
}

// ---------- pipelined streaming MFMA GEMM ----------
// Weights (head hy's 64xK hi/lo slice) resident in LDS, staged once per block.
// Block grid-strides over 64-row tiles; A loads for tile t+G prefetched into
// registers (and fp32->bf16 converted) while tile t's MFMAs run. No barriers
// in the loop. Epilogue per tile: C(bf16) + fused el/er (fp32 accuracy).
template<bool A_FP32, int K, int NHEAD>
__global__ __launch_bounds__(256) void gemm_stream(const void* __restrict__ A_any,
                                                   const unsigned short* __restrict__ BhT,
                                                   const unsigned short* __restrict__ BlT,
                                                   unsigned short* __restrict__ C,
                                                   const float* __restrict__ attn_l,
                                                   const float* __restrict__ attn_r,
                                                   float* __restrict__ el,
                                                   float* __restrict__ er, int M) {
    constexpr int KW = K + 8;
    constexpr int Nn = NHEAD * 64;
    constexpr int KB = K / 32;
    __shared__ unsigned short Bh[64][KW], Bl[64][KW];
    int hy = blockIdx.y;
    int G = gridDim.x;
    int T = (M + 63) >> 6;
    int tid = threadIdx.x;
    int wv = tid >> 6, lane = tid & 63, l15 = lane & 15, g8 = (lane >> 4) * 8;

    // stage this head's weight slice
    const unsigned short* sh_ = BhT + (size_t)hy * 64 * K;
    const unsigned short* sl_ = BlT + (size_t)hy * 64 * K;
    for (int idx = tid; idx < 64 * K / 8; idx += 256) {
        int r = idx / (K / 8), c = (idx % (K / 8)) * 8;
        *(uint4*)&Bh[r][c] = *(const uint4*)(sh_ + r * K + c);
        *(uint4*)&Bl[r][c] = *(const uint4*)(sl_ + r * K + c);
    }
    __syncthreads();

    const float* alh = attn_l + hy * 64;
    const float* arh = attn_r + hy * 64;
    float av[4], rv[4];
    #pragma unroll
    for (int c = 0; c < 4; c++) { av[c] = alh[c * 16 + l15]; rv[c] = arh[c * 16 + l15]; }

    // register tile loader
    auto load_tile = [&](int t, short8v* buf) {
        int arow = t * 64 + wv * 16 + l15;
        bool rok = arow < M;
        #pragma unroll
        for (int kk = 0; kk < KB; kk++) {
            if (A_FP32) {
                const float* A = (const float*)A_any;
                float4 v0 = {0,0,0,0}, v1 = {0,0,0,0};
                if (rok) {
                    v0 = *(const float4*)(A + (size_t)arow * K + kk * 32 + g8);
                    v1 = *(const float4*)(A + (size_t)arow * K + kk * 32 + g8 + 4);
                }
                union { unsigned short u[8]; short8v v; } cv;
                cv.u[0] = f2bf(v0.x); cv.u[1] = f2bf(v0.y);
                cv.u[2] = f2bf(v0.z); cv.u[3] = f2bf(v0.w);
                cv.u[4] = f2bf(v1.x); cv.u[5] = f2bf(v1.y);
                cv.u[6] = f2bf(v1.z); cv.u[7] = f2bf(v1.w);
                buf[kk] = cv.v;
            } else {
                const unsigned short* A = (const unsigned short*)A_any;
                uint4 raw = {0,0,0,0};
                if (rok) raw = *(const uint4*)(A + (size_t)arow * K + kk * 32 + g8);
                buf[kk] = *(short8v*)&raw;
            }
        }
    };

    short8v cur[KB], nxt[KB];
    int t = blockIdx.x;
    if (t < T) load_tile(t, cur);
    for (; t < T; t += G) {
        int tn = t + G;
        if (tn < T) load_tile(tn, nxt);          // prefetch overlaps compute below

        f32x4 acc[4] = {{0.f,0.f,0.f,0.f},{0.f,0.f,0.f,0.f},
                        {0.f,0.f,0.f,0.f},{0.f,0.f,0.f,0.f}};
        #pragma unroll
        for (int kk = 0; kk < KB; kk++) {
            #pragma unroll
            for (int c = 0; c < 4; c++) {
                short8v bh = *(short8v*)&Bh[c * 16 + l15][kk * 32 + g8];
                short8v bl = *(short8v*)&Bl[c * 16 + l15][kk * 32 + g8];
                acc[c] = __builtin_amdgcn_mfma_f32_16x16x32_bf16(cur[kk], bh, acc[c], 0, 0, 0);
                acc[c] = __builtin_amdgcn_mfma_f32_16x16x32_bf16(cur[kk], bl, acc[c], 0, 0, 0);
            }
        }

        // epilogue for tile t. C/D: col = lane&15, row = (lane>>4)*4 + j
        int row0 = t * 64;
        float elp[4] = {0.f, 0.f, 0.f, 0.f};
        float erp[4] = {0.f, 0.f, 0.f, 0.f};
        #pragma unroll
        for (int c = 0; c < 4; c++) {
            #pragma unroll
            for (int j = 0; j < 4; j++) {
                int r = row0 + wv * 16 + (lane >> 4) * 4 + j;
                if (r < M) C[(size_t)r * Nn + hy * 64 + c * 16 + l15] = f2bf(acc[c][j]);
                elp[j] += acc[c][j] * av[c];
                erp[j] += acc[c][j] * rv[c];
            }
        }
        #pragma unroll
        for (int j = 0; j < 4; j++) {
            #pragma unroll
            for (int off = 1; off < 16; off <<= 1) {
                elp[j] += __shfl_xor(elp[j], off);
                erp[j] += __shfl_xor(erp[j], off);
            }
        }
        if (l15 == 0) {
            #pragma unroll
            for (int j = 0; j < 4; j++) {
                int r = row0 + wv * 16 + (lane >> 4) * 4 + j;
                if (r < M) {
                    el[(size_t)r * NHEAD + hy] = elp[j];
                    er[(size_t)r * NHEAD + hy] = erp[j];
                }
            }
        }
        #pragma unroll
        for (int kk = 0; kk < KB; kk++) cur[kk] = nxt[kk];
    }
}

// ---------- layer1 fused per-node, single-pass softmax, unroll x8/x4/tail ----------
__global__ __launch_bounds__(256) void gat1_node(const unsigned short* __restrict__ feat,
                                                 const float* __restrict__ el,
                                                 const float* __restrict__ er,
                                                 const int* __restrict__ rowptr,
                                                 const int* __restrict__ csr_src,
                                                 const float* __restrict__ bias,
                                                 unsigned short* __restrict__ out_h, int N) {
    int node = (blockIdx.x * 256 + threadIdx.x) >> 6;
    int lane = threadIdx.x & 63;
    if (node >= N) return;
    int h = lane >> 4;
    int beg = rowptr[node], end = rowptr[node + 1];
    float erd = er[(size_t)node * 4 + h];
    float den = 0.f;
    float4 acc = {0.f, 0.f, 0.f, 0.f};
    int k = beg;
    for (; k + 7 < end; k += 8) {
        int s[8];
        #pragma unroll
        for (int u = 0; u < 8; u++) s[u] = csr_src[k + u];
        float e[8];
        #pragma unroll
        for (int u = 0; u < 8; u++) e[u] = el[(size_t)s[u] * 4 + h];
        ushort4 f[8];
        #pragma unroll
        for (int u = 0; u < 8; u++)
            f[u] = *(const ushort4*)(feat + (size_t)s[u] * 256 + lane * 4);
        #pragma unroll
        for (int u = 0; u < 8; u++) {
            float sc = e[u] + erd;
            sc = sc > 0.f ? sc : NEG_SLOPE * sc;
            float w = __expf(sc);
            den += w;
            acc.x += w * bf2f(f[u].x);
            acc.y += w * bf2f(f[u].y);
            acc.z += w * bf2f(f[u].z);
            acc.w += w * bf2f(f[u].w);
        }
    }
    for (; k + 3 < end; k += 4) {
        int s[4];
        #pragma unroll
        for (int u = 0; u < 4; u++) s[u] = csr_src[k + u];
        float e[4];
        #pragma unroll
        for (int u = 0; u < 4; u++) e[u] = el[(size_t)s[u] * 4 + h];
        ushort4 f[4];
        #pragma unroll
        for (int u = 0; u < 4; u++)
            f[u] = *(const ushort4*)(feat + (size_t)s[u] * 256 + lane * 4);
        #pragma unroll
        for (int u = 0; u < 4; u++) {
            float sc = e[u] + erd;
            sc = sc > 0.f ? sc : NEG_SLOPE * sc;
            float w = __expf(sc);
            den += w;
            acc.x += w * bf2f(f[u].x);
            acc.y += w * bf2f(f[u].y);
            acc.z += w * bf2f(f[u].z);
            acc.w += w * bf2f(f[u].w);
        }
    }
    for (; k < end; k++) {
        int s = csr_src[k];
        float sc = el[(size_t)s * 4 + h] + erd;
        sc = sc > 0.f ? sc : NEG_SLOPE * sc;
        float w = __expf(sc);
        ushort4 f = *(const ushort4*)(feat + (size_t)s * 256 + lane * 4);
        den += w;
        acc.x += w * bf2f(f.x);
        acc.y += w * bf2f(f.y);
        acc.z += w * bf2f(f.z);
        acc.w += w * bf2f(f.w);
    }
    float inv = (den > 0.f) ? 1.f / den : 0.f;
    float4 b = *(const float4*)(bias + lane * 4);
    ushort4 oh;
    oh.x = f2bf(fmaxf(acc.x * inv + b.x, 0.f));
    oh.y = f2bf(fmaxf(acc.y * inv + b.y, 0.f));
    oh.z = f2bf(fmaxf(acc.z * inv + b.z, 0.f));
    oh.w = f2bf(fmaxf(acc.w * inv + b.w, 0.f));
    *(ushort4*)(out_h + (size_t)node * 256 + lane * 4) = oh;
}

// ---------- layer2 fused per-node, single-pass + bias + relu + row-sum ----------
__global__ __launch_bounds__(256) void gat2_node(const unsigned short* __restrict__ feat,
                                                 const float* __restrict__ el,
                                                 const float* __restrict__ er,
                                                 const int* __restrict__ rowptr,
                                                 const int* __restrict__ csr_src,
                                                 const float* __restrict__ bias,
                                                 float* __restrict__ emb,
                                                 float* __restrict__ go, int N) {
    int node = (blockIdx.x * 256 + threadIdx.x) >> 6;
    int lane = threadIdx.x & 63;
    if (node >= N) return;
    int beg = rowptr[node], end = rowptr[node + 1];
    float erd = er[node];
    float den = 0.f, acc = 0.f;
    int k = beg;
    for (; k + 7 < end; k += 8) {
        int s[8];
        #pragma unroll
        for (int u = 0; u < 8; u++) s[u] = csr_src[k + u];
        float e[8];
        #pragma unroll
        for (int u = 0; u < 8; u++) e[u] = el[s[u]];
        unsigned short f[8];
        #pragma unroll
        for (int u = 0; u < 8; u++) f[u] = feat[(size_t)s[u] * 64 + lane];
        #pragma unroll
        for (int u = 0; u < 8; u++) {
            float sc = e[u] + erd;
            sc = sc > 0.f ? sc : NEG_SLOPE * sc;
            float w = __expf(sc);
            den += w;
            acc += w * bf2f(f[u]);
        }
    }
    for (; k + 3 < end; k += 4) {
        int s[4];
        #pragma unroll
        for (int u = 0; u < 4; u++) s[u] = csr_src[k + u];
        float e[4];
        #pragma unroll
        for (int u = 0; u < 4; u++) e[u] = el[s[u]];
        unsigned short f[4];
        #pragma unroll
        for (int u = 0; u < 4; u++) f[u] = feat[(size_t)s[u] * 64 + lane];
        #pragma unroll
        for (int u = 0; u < 4; u++) {
            float sc = e[u] + erd;
            sc = sc > 0.f ? sc : NEG_SLOPE * sc;
            float w = __expf(sc);
            den += w;
            acc += w * bf2f(f[u]);
        }
    }
    for (; k < end; k++) {
        int s = csr_src[k];
        float sc = el[s] + erd;
        sc = sc > 0.f ? sc : NEG_SLOPE * sc;
        float w = __expf(sc);
        den += w;
        acc += w * bf2f(feat[(size_t)s * 64 + lane]);
    }
    float inv = (den > 0.f) ? 1.f / den : 0.f;
    float v = fmaxf(acc * inv + bias[lane], 0.f);
    go[(size_t)node * 64 + lane] = v;
    float sum = v;
    #pragma unroll
    for (int off = 1; off < 64; off <<= 1) sum += __shfl_xor(sum, off);
    if (lane == 0) emb[node] = sum;
}

extern "C" void kernel_launch(void* const* d_in, const int* in_sizes, int n_in,
                              void* d_out, int out_size, void* d_ws, size_t ws_size,
                              hipStream_t stream) {
    const float* x   = (const float*)d_in[0];
    const int*   src = (const int*)d_in[1];
    const int*   dst = (const int*)d_in[2];
    const float* W1  = (const float*)d_in[3];
    const float* al1 = (const float*)d_in[4];
    const float* ar1 = (const float*)d_in[5];
    const float* b1  = (const float*)d_in[6];
    const float* W2  = (const float*)d_in[7];
    const float* al2 = (const float*)d_in[8];
    const float* ar2 = (const float*)d_in[9];
    const float* b2  = (const float*)d_in[10];
    const int N = in_sizes[0] / 128;
    const int E = in_sizes[1];
    const int NB = (N + 255) / 256;

    char* base = (char*)d_ws;
    size_t off = 0;
    auto alloc = [&](size_t bytes) {
        off = (off + 255) & ~(size_t)255;
        void* p = base + off;
        off += bytes;
        return p;
    };
    unsigned short* feat1 = (unsigned short*)alloc((size_t)N * 256 * 2);
    unsigned short* feat2 = (unsigned short*)alloc((size_t)N * 64 * 2);
    float* el1   = (float*)alloc((size_t)N * 4 * 4);
    float* er1   = (float*)alloc((size_t)N * 4 * 4);
    float* el2   = (float*)alloc((size_t)N * 4);
    float* er2   = (float*)alloc((size_t)N * 4);
    int* icounts = (int*)alloc((size_t)N * 4);
    int* icursor = (int*)alloc((size_t)N * 4);
    int* ibsum   = (int*)alloc((size_t)(NB + 1) * 4);
    int* irowp   = (int*)alloc((size_t)(N + 1) * 4);
    int* icsrs   = (int*)alloc((size_t)E * 4);
    unsigned short* w1th = (unsigned short*)alloc((size_t)128 * 256 * 2);
    unsigned short* w1tl = (unsigned short*)alloc((size_t)128 * 256 * 2);
    unsigned short* hh   = (unsigned short*)alloc((size_t)N * 256 * 2);
    unsigned short* w2th = (unsigned short*)alloc((size_t)256 * 64 * 2);
    unsigned short* w2tl = (unsigned short*)alloc((size_t)256 * 64 * 2);
    (void)ws_size;

    // 1. zero counts
    hipMemsetAsync(icounts, 0, (size_t)N * 4, stream);

    // 2. hist + weight split (fused)
    {
        int histB = (E + 255) / 256;
        int splitB = (128 * 256 + 256 * 64 + 255) / 256;
        hist_split_kernel<<<histB + splitB, 256, 0, stream>>>(
            dst, icounts, E, histB, W1, w1th, w1tl, W2, w2th, w2tl);
    }

    // 3-5. scan chain -> rowptr + cursor
    bsum_kernel<<<NB, 256, 0, stream>>>(icounts, ibsum, N);
    bscan_kernel<<<1, 256, 0, stream>>>(ibsum, NB, irowp, N, E);
    rowptr_kernel<<<NB, 256, 0, stream>>>(icounts, ibsum, irowp, icursor, N);

    // 6. CSR fill
    fill_kernel<<<(E + 255) / 256, 256, 0, stream>>>(src, dst, icursor, icsrs, E);

    // 7. gemm1: x @ W1 (+ el/er epilogue), pipelined streaming
    {
        dim3 g(256, 4);
        gemm_stream<true, 128, 4><<<g, 256, 0, stream>>>(x, w1th, w1tl, feat1,
                                                         al1, ar1, el1, er1, N);
    }

    // 8. layer-1 attention aggregate
    gat1_node<<<(N + 3) / 4, 256, 0, stream>>>(feat1, el1, er1, irowp, icsrs, b1, hh, N);

    // 9. gemm2: h @ W2 (+ el/er epilogue)
    {
        dim3 g(512, 1);
        gemm_stream<false, 256, 1><<<g, 256, 0, stream>>>(hh, w2th, w2tl, feat2,
                                                          al2, ar2, el2, er2, N);
    }

    // 10. layer-2 attention aggregate + bias + relu + row-sum
    gat2_node<<<(N + 3) / 4, 256, 0, stream>>>(feat2, el2, er2, irowp, icsrs, b2,
                                               (float*)d_out, (float*)d_out + N, N);
}